// Round 3
// baseline (17849.695 us; speedup 1.0000x reference)
//
#include <hip/hip_runtime.h>
#include <hip/hip_bf16.h>

typedef __hip_bfloat16 bf16;

__device__ __forceinline__ float cvt(bf16 v) { return __bfloat162float(v); }

// runtime-dtype helpers: bf==true -> bf16, else fp32
__device__ __forceinline__ float ldg_any(const void* p, size_t i, bool bf) {
    return bf ? cvt(((const bf16*)p)[i]) : ((const float*)p)[i];
}
__device__ __forceinline__ void stg_any(void* p, size_t i, float v, bool bf) {
    if (bf) ((bf16*)p)[i] = __float2bfloat16(v);
    else    ((float*)p)[i] = v;
}
// mode: 0 = fp32 fixed, 1 = bf16 fixed, 2 = use detected flag
__device__ __forceinline__ bool bfmode(int mode, const int* flags) {
    return mode == 2 ? (flags[0] != 0) : (mode != 0);
}

// ---------------------------------------------------------------------------
// dtype probe on f3 (random N(0,1)): fp32 data never has fp32-exponent >= 200;
// bf16-packed data puts a bf16 exponent into the fp32 exponent field.
// ---------------------------------------------------------------------------
__global__ void detect_k(const unsigned int* __restrict__ x, int* __restrict__ flags)
{
    unsigned int u = x[threadIdx.x];
    int e = (u >> 23) & 0xFF;
    unsigned long long m = __ballot(e >= 200);
    if (threadIdx.x == 0) flags[0] = (m != 0ULL) ? 1 : 0;
}

// ---------------------------------------------------------------------------
// 3x3 SAME conv, stride 1. in: runtime dtype via inm; w/bias/scale: model
// inputs (flag dtype) with element offset w_off; out: runtime dtype via outm
// at element offset out_off. fp32 accumulate in LDS-staged tiles.
// ---------------------------------------------------------------------------
__global__ __launch_bounds__(256) void conv3x3_k(
    const void* __restrict__ in, int inm,
    const void* __restrict__ w, size_t w_off,
    const void* __restrict__ bias, const void* __restrict__ scale, int sidx,
    void* __restrict__ out, int outm, size_t out_off,
    const int* __restrict__ flags,
    int Cin, int H, int W, int Cout)
{
    const bool fin  = bfmode(inm, flags);
    const bool fw   = flags[0] != 0;
    const bool fout = bfmode(outm, flags);

    const int t  = threadIdx.x;
    const int tx = t & 31, ty = t >> 5;
    const int strips = (W + 63) >> 6;
    const int y   = blockIdx.x / strips;
    const int x0  = (blockIdx.x - y * strips) << 6;
    const int co0 = blockIdx.y << 6;
    const int n   = blockIdx.z;
    const int HW  = H * W;

    __shared__ float s_in[16 * 3 * 66];   // [ci][ky][x0-1 .. x0+64]
    __shared__ float s_w[64 * 145];       // [co][ci*9+tap], padded stride 145

    float acc[8][2];
#pragma unroll
    for (int k = 0; k < 8; ++k) { acc[k][0] = 0.f; acc[k][1] = 0.f; }

    const size_t inbase = (size_t)n * Cin * HW;

    for (int ci0 = 0; ci0 < Cin; ci0 += 16) {
        __syncthreads();
        for (int e = t; e < 16 * 3 * 66; e += 256) {
            int ci = e / 198; int r = e - ci * 198; int ky = r / 66; int xx = r - ky * 66;
            int gy = y + ky - 1, gx = x0 + xx - 1;
            float v = 0.f;
            if ((unsigned)gy < (unsigned)H && (unsigned)gx < (unsigned)W)
                v = ldg_any(in, inbase + (size_t)(ci0 + ci) * HW + (size_t)gy * W + gx, fin);
            s_in[e] = v;
        }
        {
            int co = t >> 2, j0 = (t & 3) * 36;
            int gco = co0 + co;
            if (gco < Cout) {
                size_t wbase = w_off + ((size_t)gco * Cin + ci0) * 9 + j0;
#pragma unroll
                for (int k2 = 0; k2 < 36; ++k2) s_w[co * 145 + j0 + k2] = ldg_any(w, wbase + k2, fw);
            } else {
#pragma unroll
                for (int k2 = 0; k2 < 36; ++k2) s_w[co * 145 + j0 + k2] = 0.f;
            }
        }
        __syncthreads();

        for (int ci = 0; ci < 16; ++ci) {
#pragma unroll
            for (int tap = 0; tap < 9; ++tap) {
                const int ky = tap / 3, kx = tap - ky * 3;
                float in0 = s_in[ci * 198 + ky * 66 + tx + kx];
                float in1 = s_in[ci * 198 + ky * 66 + tx + 32 + kx];
#pragma unroll
                for (int k = 0; k < 8; ++k) {
                    float wv = s_w[(k * 8 + ty) * 145 + ci * 9 + tap];
                    acc[k][0] = fmaf(wv, in0, acc[k][0]);
                    acc[k][1] = fmaf(wv, in1, acc[k][1]);
                }
            }
        }
    }

    const float al = scale ? ldg_any(scale, sidx, fw) : 1.f;
#pragma unroll
    for (int k = 0; k < 8; ++k) {
        int co = co0 + k * 8 + ty;
        if (co >= Cout) continue;
        float bv = bias ? ldg_any(bias, co, fw) : 0.f;
        size_t op = out_off + ((size_t)n * Cout + co) * HW + (size_t)y * W;
        int xA = x0 + tx, xB = xA + 32;
        if (xA < W) stg_any(out, op + xA, fmaf(al, acc[k][0], bv), fout);
        if (xB < W) stg_any(out, op + xB, fmaf(al, acc[k][1], bv), fout);
    }
}

// ---------------------------------------------------------------------------
// GroupNorm on bf16 intermediates (two-pass, fp32 atomic partial sums).
// ---------------------------------------------------------------------------
__global__ __launch_bounds__(256) void gn_stats_k(const bf16* __restrict__ x,
                                                  float* __restrict__ stats, int per_group)
{
    const int g = blockIdx.x;
    const bf16* xp = x + (size_t)g * per_group;
    float s = 0.f, ss = 0.f;
    const int stride = 256 * gridDim.y;
    for (int i = blockIdx.y * 256 + threadIdx.x; i < per_group; i += stride) {
        float v = cvt(xp[i]); s += v; ss = fmaf(v, v, ss);
    }
#pragma unroll
    for (int off = 32; off > 0; off >>= 1) {
        s  += __shfl_down(s,  off, 64);
        ss += __shfl_down(ss, off, 64);
    }
    __shared__ float sh[8];
    const int wv = threadIdx.x >> 6;
    if ((threadIdx.x & 63) == 0) { sh[wv * 2] = s; sh[wv * 2 + 1] = ss; }
    __syncthreads();
    if (threadIdx.x == 0) {
        s  = sh[0] + sh[2] + sh[4] + sh[6];
        ss = sh[1] + sh[3] + sh[5] + sh[7];
        atomicAdd(&stats[2 * g],     s);
        atomicAdd(&stats[2 * g + 1], ss);
    }
}

__global__ void gn_apply_k(bf16* __restrict__ x, const float* __restrict__ stats,
                           const void* __restrict__ gamma, const void* __restrict__ beta,
                           size_t gb_off, const int* __restrict__ flags,
                           int HW, int C, int per_group, float inv_len, int relu, long total)
{
    const bool fw = flags[0] != 0;
    long i = (long)blockIdx.x * blockDim.x + threadIdx.x;
    if (i >= total) return;
    int gl = (int)(i / per_group);
    int c  = (int)((i / HW) % C);
    float mu  = stats[2 * gl] * inv_len;
    float var = fmaxf(stats[2 * gl + 1] * inv_len - mu * mu, 0.f);
    float inv = rsqrtf(var + 1e-5f);
    float v = (cvt(x[i]) - mu) * inv * ldg_any(gamma, gb_off + c, fw)
              + ldg_any(beta, gb_off + c, fw);
    if (relu) v = fmaxf(v, 0.f);
    x[i] = __float2bfloat16(v);
}

// ---------------------------------------------------------------------------
__global__ void extract_params_k(const void* __restrict__ pred3, const int* __restrict__ flags,
                                 float* __restrict__ prm, int HW)
{
    const bool bf = flags[0] != 0;
    int tid = blockIdx.x * blockDim.x + threadIdx.x;
    if (tid >= 200 * 169) return;
    int p = tid / 169, c = tid - p * 169;
    int b = p / 100, i = p - b * 100;       // first 100 flat pixels = row 0, x=i
    prm[tid] = ldg_any(pred3, ((size_t)b * 254 + 85 + c) * HW + i, bf);
}

__global__ void upsample_add_k(const bf16* __restrict__ src, bf16* __restrict__ dst,
                               int h, int w, int OH, int OW, long total)
{
    long i = (long)blockIdx.x * blockDim.x + threadIdx.x;
    if (i >= total) return;
    int ox = (int)(i % OW);
    long r = i / OW;
    int oy = (int)(r % OH);
    int nc = (int)(r / OH);
    float sy = oy * ((h - 1.f) / (OH - 1.f));
    float sx = ox * ((w - 1.f) / (OW - 1.f));
    int y0 = (int)sy; int y1 = min(y0 + 1, h - 1); float wy = sy - y0;
    int x0 = (int)sx; int x1 = min(x0 + 1, w - 1); float wx = sx - x0;
    const bf16* sp = src + (size_t)nc * h * w;
    float t0 = cvt(sp[y0 * w + x0]) * (1.f - wy) + cvt(sp[y1 * w + x0]) * wy;
    float t1 = cvt(sp[y0 * w + x1]) * (1.f - wy) + cvt(sp[y1 * w + x1]) * wy;
    float v = cvt(dst[i]) + t0 * (1.f - wx) + t1 * wx;
    dst[i] = __float2bfloat16(v);
}

__global__ void resize_out_k(const float* __restrict__ src, void* __restrict__ dst,
                             size_t dst_off, const int* __restrict__ flags,
                             int h, int w, int OH, int OW, long total)
{
    const bool bf = flags[0] != 0;
    long i = (long)blockIdx.x * blockDim.x + threadIdx.x;
    if (i >= total) return;
    int ox = (int)(i % OW);
    long r = i / OW;
    int oy = (int)(r % OH);
    int nc = (int)(r / OH);
    float sy = oy * ((h - 1.f) / (OH - 1.f));
    float sx = ox * ((w - 1.f) / (OW - 1.f));
    int y0 = (int)sy; int y1 = min(y0 + 1, h - 1); float wy = sy - y0;
    int x0 = (int)sx; int x1 = min(x0 + 1, w - 1); float wx = sx - x0;
    const float* sp = src + (size_t)nc * h * w;
    float t0 = sp[y0 * w + x0] * (1.f - wy) + sp[y1 * w + x0] * wy;
    float t1 = sp[y0 * w + x1] * (1.f - wy) + sp[y1 * w + x1] * wy;
    stg_any(dst, dst_off + (size_t)i, t0 * (1.f - wx) + t1 * wx, bf);
}

__global__ void cast_out_k(const bf16* __restrict__ src, void* __restrict__ dst,
                           size_t dst_off, const int* __restrict__ flags, long n)
{
    const bool bf = flags[0] != 0;
    long i = (long)blockIdx.x * blockDim.x + threadIdx.x;
    if (i < n) stg_any(dst, dst_off + (size_t)i, cvt(src[i]), bf);
}

__global__ void conv1x1_k(const bf16* __restrict__ in, const void* __restrict__ w,
                          const int* __restrict__ flags,
                          bf16* __restrict__ out, int N, int Cin, int Cout, int HW)
{
    const bool fw = flags[0] != 0;
    long total = (long)N * Cout * HW;
    long idx = (long)blockIdx.x * blockDim.x + threadIdx.x;
    if (idx >= total) return;
    int p  = (int)(idx % HW);
    int co = (int)((idx / HW) % Cout);
    int n  = (int)(idx / ((long)HW * Cout));
    float s = 0.f;
    const bf16* ip = in + (size_t)n * Cin * HW + p;
    for (int ci = 0; ci < Cin; ++ci)
        s = fmaf(ldg_any(w, (size_t)co * Cin + ci, fw), cvt(ip[(size_t)ci * HW]), s);
    out[idx] = __float2bfloat16(s);
}

__global__ __launch_bounds__(256) void dyn_conv_k(const bf16* __restrict__ mf,
                                                  const float* __restrict__ prm,
                                                  float* __restrict__ out, int H, int W)
{
    const int inst = blockIdx.y;
    __shared__ float p[169];
    if (threadIdx.x < 169) p[threadIdx.x] = prm[inst * 169 + threadIdx.x];
    __syncthreads();
    const int HW = H * W;
    const int pix = blockIdx.x * 256 + threadIdx.x;
    if (pix >= HW) return;
    const int b = inst / 100;
    float xin[10];
#pragma unroll
    for (int c = 0; c < 8; ++c) xin[c] = cvt(mf[((size_t)(b * 8 + c)) * HW + pix]);
    int yy = pix / W, xx = pix - yy * W;
    xin[8] = -1.f + 2.f * xx / (W - 1);
    xin[9] = -1.f + 2.f * yy / (H - 1);
    float h1[8];
#pragma unroll
    for (int o = 0; o < 8; ++o) {
        float s = p[152 + o];
#pragma unroll
        for (int c = 0; c < 10; ++c) s = fmaf(p[o * 10 + c], xin[c], s);
        h1[o] = fmaxf(s, 0.f);
    }
    float h2[8];
#pragma unroll
    for (int o = 0; o < 8; ++o) {
        float s = p[160 + o];
#pragma unroll
        for (int c = 0; c < 8; ++c) s = fmaf(p[80 + o * 8 + c], h1[c], s);
        h2[o] = fmaxf(s, 0.f);
    }
    float s = p[168];
#pragma unroll
    for (int c = 0; c < 8; ++c) s = fmaf(p[144 + c], h2[c], s);
    out[(size_t)inst * HW + pix] = s;
}

// ---------------------------------------------------------------------------
static inline void launch_conv(const void* in, int inm, const void* w, size_t w_off,
                               const void* bias, const void* scale, int sidx,
                               void* out, int outm, size_t out_off, const int* flags,
                               int N, int Cin, int H, int W, int Cout, hipStream_t s)
{
    int strips = (W + 63) / 64;
    dim3 g(H * strips, (Cout + 63) / 64, N);
    conv3x3_k<<<g, 256, 0, s>>>(in, inm, w, w_off, bias, scale, sidx,
                                out, outm, out_off, flags, Cin, H, W, Cout);
}

static inline void run_gn(bf16* x, float** st, const void* g, const void* b, size_t gb_off,
                          const int* flags, int N, int C, int G, int HW, bool relu,
                          hipStream_t s)
{
    int per_group = (C / G) * HW;
    int ngroups = N * G;
    int chunks = per_group / 8192; if (chunks < 1) chunks = 1; if (chunks > 64) chunks = 64;
    gn_stats_k<<<dim3(ngroups, chunks), 256, 0, s>>>(x, *st, per_group);
    long total = (long)N * C * HW;
    gn_apply_k<<<(int)((total + 255) / 256), 256, 0, s>>>(
        x, *st, g, b, gb_off, flags, HW, C, per_group, 1.f / per_group, relu ? 1 : 0, total);
    *st += 2 * ngroups;
}

extern "C" void kernel_launch(void* const* d_in, const int* in_sizes, int n_in,
                              void* d_out, int out_size, void* d_ws, size_t ws_size,
                              hipStream_t stream)
{
    const void* f[5] = {d_in[0], d_in[1], d_in[2], d_in[3], d_in[4]};
    static const int Hs[5] = {96, 48, 24, 12, 6};
    static const int Wd[5] = {160, 80, 40, 20, 10};
    const void* head_w     = d_in[5];
    const void* head_gn_g  = d_in[6];
    const void* head_gn_b  = d_in[7];
    const void* head_out_w = d_in[8];
    const void* head_out_b = d_in[9];
    const void* scales     = d_in[10];
    const void* ref_w      = d_in[11];
    const void* ref_gn_g   = d_in[12];
    const void* ref_gn_b   = d_in[13];
    const void* tow_w      = d_in[14];
    const void* tow_gn_g   = d_in[15];
    const void* tow_gn_b   = d_in[16];
    const void* out_w      = d_in[17];
    const void* out_gn_g   = d_in[18];
    const void* out_gn_b   = d_in[19];

    // output element offsets (dtype-independent)
    size_t po[5]; size_t off = 0;
    for (int l = 0; l < 5; ++l) { po[l] = off; off += (size_t)2 * 254 * Hs[l] * Wd[l]; }
    size_t mf_off = off; off += 245760;
    size_t ml_off = off;

    // ---- workspace: all scratch in d_ws (~32.1 MB) ----
    bf16*  bufA  = (bf16*)d_ws;                 // 7,864,320 bf16
    bf16*  bufB  = bufA + 7864320;              // 7,864,320 bf16
    bf16*  mfeat = bufB + 7864320;              // 245,760 bf16
    float* prm   = (float*)(mfeat + 245760);    // 33,800 f32
    float* stats = prm + 33800;                 // 4,096 f32
    int*   flags = (int*)(stats + 4096);        // 16 ints
    float* dyn   = (float*)bufA;                // aliases bufA after its last read

    hipMemsetAsync(stats, 0, 4096 * sizeof(float), stream);
    detect_k<<<1, 64, 0, stream>>>((const unsigned int*)d_in[0], flags);
    float* st = stats;

    const size_t HEADW_L = 589824;   // 256*256*9 elements
    const size_t REFW_L  = 294912;   // 128*256*9
    const size_t TOWW_L  = 147456;   // 128*128*9

    // ---------------- head branches ----------------
    for (int lvl = 0; lvl < 5; ++lvl) {
        int H = Hs[lvl], W = Wd[lvl], HW = H * W;
        launch_conv(f[lvl], 2, head_w, 0, nullptr, nullptr, 0, bufA, 1, 0,
                    flags, 2, 256, H, W, 256, stream);
        run_gn(bufA, &st, head_gn_g, head_gn_b, 0, flags, 2, 256, 32, HW, true, stream);
        bf16* a = bufA; bf16* bb = bufB;
        for (int l = 1; l < 4; ++l) {
            launch_conv(a, 1, head_w, (size_t)l * HEADW_L, nullptr, nullptr, 0,
                        bb, 1, 0, flags, 2, 256, H, W, 256, stream);
            run_gn(bb, &st, head_gn_g, head_gn_b, (size_t)l * 256, flags,
                   2, 256, 32, HW, true, stream);
            bf16* tmp = a; a = bb; bb = tmp;
        }
        launch_conv(a, 1, head_out_w, 0, head_out_b, scales, lvl, d_out, 2, po[lvl],
                    flags, 2, 256, H, W, 254, stream);
        if (lvl == 0)
            extract_params_k<<<(200 * 169 + 255) / 256, 256, 0, stream>>>(d_out, flags, prm, HW);
    }

    // ---------------- mask branch ----------------
    {
        int H = 96, W = 160, HW = H * W;
        launch_conv(f[0], 2, ref_w, 0, nullptr, nullptr, 0, bufA, 1, 0,
                    flags, 2, 256, H, W, 128, stream);
        run_gn(bufA, &st, ref_gn_g, ref_gn_b, 0, flags, 2, 128, 1, HW, true, stream);
        for (int i = 1; i < 3; ++i) {
            int h = Hs[i], w2 = Wd[i];
            launch_conv(f[i], 2, ref_w, (size_t)i * REFW_L, nullptr, nullptr, 0,
                        bufB, 1, 0, flags, 2, 256, h, w2, 128, stream);
            run_gn(bufB, &st, ref_gn_g, ref_gn_b, (size_t)i * 128, flags,
                   2, 128, 1, h * w2, true, stream);
            long tot = (long)2 * 128 * HW;
            upsample_add_k<<<(int)((tot + 255) / 256), 256, 0, stream>>>(bufB, bufA, h, w2, H, W, tot);
        }
        bf16* a = bufA; bf16* bb = bufB;
        for (int l = 0; l < 4; ++l) {
            launch_conv(a, 1, tow_w, (size_t)l * TOWW_L, nullptr, nullptr, 0,
                        bb, 1, 0, flags, 2, 128, H, W, 128, stream);
            run_gn(bb, &st, tow_gn_g, tow_gn_b, (size_t)l * 128, flags,
                   2, 128, 1, HW, true, stream);
            bf16* tmp = a; a = bb; bb = tmp;
        }
        // tower ends in bufA
        conv1x1_k<<<(2 * 8 * HW + 255) / 256, 256, 0, stream>>>(a, out_w, flags, mfeat, 2, 128, 8, HW);
        run_gn(mfeat, &st, out_gn_g, out_gn_b, 0, flags, 2, 8, 1, HW, true, stream);
        cast_out_k<<<(2 * 8 * HW + 255) / 256, 256, 0, stream>>>(mfeat, d_out, mf_off, flags, (long)2 * 8 * HW);
        // dynamic conv (dyn aliases bufA; tower output already consumed)
        dyn_conv_k<<<dim3((HW + 255) / 256, 200), 256, 0, stream>>>(mfeat, prm, dyn, H, W);
        long nt = (long)200 * 192 * 320;
        resize_out_k<<<(int)((nt + 255) / 256), 256, 0, stream>>>(dyn, d_out, ml_off, flags, 96, 160, 192, 320, nt);
    }
}

// Round 4
// 5806.374 us; speedup vs baseline: 3.0742x; 3.0742x over previous
//
#include <hip/hip_runtime.h>
#include <hip/hip_bf16.h>

typedef __hip_bfloat16 bf16;
typedef short v8s __attribute__((ext_vector_type(8)));
typedef float v4f __attribute__((ext_vector_type(4)));

__device__ __forceinline__ float cvt(bf16 v) { return __bfloat162float(v); }

__device__ __forceinline__ float ldg_any(const void* p, size_t i, bool bf) {
    return bf ? cvt(((const bf16*)p)[i]) : ((const float*)p)[i];
}
__device__ __forceinline__ void stg_any(void* p, size_t i, float v, bool bf) {
    if (bf) ((bf16*)p)[i] = __float2bfloat16(v);
    else    ((float*)p)[i] = v;
}
__device__ __forceinline__ bool bfmode(int mode, const int* flags) {
    return mode == 2 ? (flags[0] != 0) : (mode != 0);
}
__device__ __forceinline__ unsigned short f2b(float f) {
    bf16 h = __float2bfloat16(f); return *(unsigned short*)&h;
}
__device__ __forceinline__ void b2f2(unsigned u, float& a, float& b) {
    a = __uint_as_float(u << 16);
    b = __uint_as_float(u & 0xffff0000u);
}

// ---------------------------------------------------------------------------
// dtype probe on f3 (N(0,1) data): fp32 never has exponent >= 200.
// ---------------------------------------------------------------------------
__global__ void detect_k(const unsigned int* __restrict__ x, int* __restrict__ flags)
{
    unsigned int u = x[threadIdx.x];
    int e = (u >> 23) & 0xFF;
    unsigned long long m = __ballot(e >= 200);
    if (threadIdx.x == 0) flags[0] = (m != 0ULL) ? 1 : 0;
}

// ---------------------------------------------------------------------------
// weight repack: OIHW -> [tap][co(pad)][ci] bf16  (zero-pad co >= Cout)
// ---------------------------------------------------------------------------
__global__ void repack_k(const void* __restrict__ w, const int* __restrict__ flags,
                         bf16* __restrict__ dst, int Cout, int Cpad, int Cin, int total)
{
    const bool fw = flags[0] != 0;
    int i = blockIdx.x * 256 + threadIdx.x;
    if (i >= total) return;
    int ci = i % Cin; int r = i / Cin; int co = r % Cpad; int tap = r / Cpad;
    float v = 0.f;
    if (co < Cout) v = ldg_any(w, ((size_t)co * Cin + ci) * 9 + tap, fw);
    dst[i] = __float2bfloat16(v);
}

// ---------------------------------------------------------------------------
// MFMA implicit-GEMM 3x3 SAME conv.
// Block tile: 128 co x (8 rows x 32 cols) pixels. 4 waves; each wave:
// 8 m-frags (16 co) x 4 n-frags (rows 2wv..2wv+1, col halves).
// K loop: Cin in chunks of 32; 9 taps per chunk (1 MFMA K-step each).
// Optional fused input GroupNorm+ReLU (stats from previous layer) applied in
// the LDS staging path. Optional epilogue alpha/bias (head_out).
// ---------------------------------------------------------------------------
__global__ __launch_bounds__(256) void conv3x3_mfma_k(
    const void* __restrict__ in, int inm,
    const bf16* __restrict__ wrep,
    const float* __restrict__ gstat, const void* __restrict__ gamma,
    const void* __restrict__ beta, size_t gb_off, int cpg, int Gn, float inv_pg,
    const void* __restrict__ bias, const void* __restrict__ scale, int sidx,
    void* __restrict__ out, int outm, size_t out_off,
    const int* __restrict__ flags,
    int Cin, int H, int W, int Cout, int Cpad, int co_blocks)
{
    const bool fin  = bfmode(inm, flags);
    const bool fw   = flags[0] != 0;
    const bool fout = bfmode(outm, flags);
    const int HW = H * W;

    const int t    = threadIdx.x;
    const int lane = t & 63;
    const int wv   = t >> 6;
    const int c    = lane & 15;
    const int quad = lane >> 4;
    const int x0   = blockIdx.x * 32;
    const int y0   = blockIdx.y * 8;
    const int n    = blockIdx.z / co_blocks;
    const int cb   = blockIdx.z % co_blocks;

    __shared__ __align__(16) bf16 s_b[340 * 40];   // [pos=rr*34+cc][ci swizzled]
    __shared__ float s_scale[256], s_shift[256];

    // per-input-channel norm precompute
    if (gstat) {
        for (int ch = t; ch < Cin; ch += 256) {
            int gl = n * Gn + ch / cpg;
            float mu  = gstat[2 * gl] * inv_pg;
            float var = fmaxf(gstat[2 * gl + 1] * inv_pg - mu * mu, 0.f);
            float iv  = rsqrtf(var + 1e-5f);
            float ga  = ldg_any(gamma, gb_off + ch, fw);
            float be  = ldg_any(beta,  gb_off + ch, fw);
            s_scale[ch] = iv * ga;
            s_shift[ch] = be - mu * iv * ga;
        }
    }
    const bool donorm = (gstat != nullptr);

    v4f acc[8][4];
#pragma unroll
    for (int i = 0; i < 8; ++i)
#pragma unroll
        for (int j = 0; j < 4; ++j) acc[i][j] = v4f{0.f, 0.f, 0.f, 0.f};

    const size_t inbase = (size_t)n * Cin * HW;
    // A-fragment per-lane base: co = cb*128 + mf*16 + c, k-octet = quad
    const size_t a_base = ((size_t)cb * 128 + c) * Cin + quad * 8;

    const int s_ci  = t >> 3;      // staging: this thread's channel within chunk
    const int s_p0  = t & 7;       // staging: starting pos

    for (int ci0 = 0; ci0 < Cin; ci0 += 32) {
        __syncthreads();
        {
            float sc = 1.f, sh = 0.f;
            if (donorm) { sc = s_scale[ci0 + s_ci]; sh = s_shift[ci0 + s_ci]; }
            const size_t cbase = inbase + (size_t)(ci0 + s_ci) * HW;
            for (int pos = s_p0; pos < 340; pos += 8) {
                int rr = pos / 34, cc2 = pos - rr * 34;
                int gy = y0 + rr - 1, gx = x0 + cc2 - 1;
                float v = 0.f;
                if ((unsigned)gy < (unsigned)H && (unsigned)gx < (unsigned)W) {
                    v = ldg_any(in, cbase + (size_t)gy * W + gx, fin);
                    if (donorm) v = fmaxf(fmaf(v, sc, sh), 0.f);
                }
                int slot = (((s_ci >> 3) + pos) & 3) * 8 + (s_ci & 7);
                s_b[pos * 40 + slot] = __float2bfloat16(v);
            }
        }
        __syncthreads();

#pragma unroll
        for (int tap = 0; tap < 9; ++tap) {
            const int ky = tap / 3, kx = tap - ky * 3;
            // B fragments: nf = (row, col-half)
            v8s bfr[4];
#pragma unroll
            for (int nf = 0; nf < 4; ++nf) {
                int pos = (2 * wv + (nf >> 1) + ky) * 34 + c + (nf & 1) * 16 + kx;
                bfr[nf] = *(const v8s*)&s_b[pos * 40 + (((quad + pos) & 3) * 8)];
            }
            const bf16* wt = wrep + a_base + ci0 + ((size_t)tap * Cpad) * Cin;
#pragma unroll
            for (int mf = 0; mf < 8; ++mf) {
                v8s af = *(const v8s*)(wt + (size_t)mf * 16 * Cin);
#pragma unroll
                for (int nf = 0; nf < 4; ++nf)
                    acc[mf][nf] = __builtin_amdgcn_mfma_f32_16x16x32_bf16(
                        af, bfr[nf], acc[mf][nf], 0, 0, 0);
            }
        }
    }

    // epilogue: C/D layout col=lane&15, row=quad*4+reg
    const float al = scale ? ldg_any(scale, sidx, fw) : 1.f;
#pragma unroll
    for (int mf = 0; mf < 8; ++mf) {
        int cobase = cb * 128 + mf * 16 + quad * 4;
#pragma unroll
        for (int reg = 0; reg < 4; ++reg) {
            int co = cobase + reg;
            if (co >= Cout) continue;
            float bv = bias ? ldg_any(bias, co, fw) : 0.f;
            size_t obase = out_off + ((size_t)n * Cout + co) * HW;
#pragma unroll
            for (int nf = 0; nf < 4; ++nf) {
                int y = y0 + 2 * wv + (nf >> 1);
                int x = x0 + (nf & 1) * 16 + c;
                if (y < H && x < W)
                    stg_any(out, obase + (size_t)y * W + x,
                            fmaf(al, acc[mf][nf][reg], bv), fout);
            }
        }
    }
}

// ---------------------------------------------------------------------------
// GroupNorm stats (vectorized bf16x8), atomic fp32 partials per group.
// ---------------------------------------------------------------------------
__global__ __launch_bounds__(256) void gn_stats_v(const bf16* __restrict__ x,
                                                  float* __restrict__ stats, int per_group)
{
    const int g = blockIdx.x;
    const uint4* xp = (const uint4*)(x + (size_t)g * per_group);
    const int nvec = per_group >> 3;
    float s = 0.f, ss = 0.f;
    const int stride = 256 * gridDim.y;
    for (int i = blockIdx.y * 256 + threadIdx.x; i < nvec; i += stride) {
        uint4 u = xp[i];
        float f0,f1,f2,f3,f4,f5,f6,f7;
        b2f2(u.x, f0, f1); b2f2(u.y, f2, f3); b2f2(u.z, f4, f5); b2f2(u.w, f6, f7);
        s += ((f0+f1)+(f2+f3)) + ((f4+f5)+(f6+f7));
        ss = fmaf(f0,f0,ss); ss = fmaf(f1,f1,ss); ss = fmaf(f2,f2,ss); ss = fmaf(f3,f3,ss);
        ss = fmaf(f4,f4,ss); ss = fmaf(f5,f5,ss); ss = fmaf(f6,f6,ss); ss = fmaf(f7,f7,ss);
    }
#pragma unroll
    for (int off = 32; off > 0; off >>= 1) {
        s  += __shfl_down(s,  off, 64);
        ss += __shfl_down(ss, off, 64);
    }
    __shared__ float sh[8];
    const int wv = threadIdx.x >> 6;
    if ((threadIdx.x & 63) == 0) { sh[wv * 2] = s; sh[wv * 2 + 1] = ss; }
    __syncthreads();
    if (threadIdx.x == 0) {
        s  = sh[0] + sh[2] + sh[4] + sh[6];
        ss = sh[1] + sh[3] + sh[5] + sh[7];
        atomicAdd(&stats[2 * g],     s);
        atomicAdd(&stats[2 * g + 1], ss);
    }
}

// GroupNorm apply + relu (vectorized; requires HW%8==0 at call sites)
__global__ void gn_apply_v(bf16* __restrict__ x, const float* __restrict__ stats,
                           const void* __restrict__ gamma, const void* __restrict__ beta,
                           size_t gb_off, const int* __restrict__ flags,
                           int HW, int C, int per_group, float inv_len, long nvec)
{
    const bool fw = flags[0] != 0;
    long v = (long)blockIdx.x * blockDim.x + threadIdx.x;
    if (v >= nvec) return;
    long i0 = v * 8;
    int gl = (int)(i0 / per_group);
    float mu  = stats[2 * gl] * inv_len;
    float var = fmaxf(stats[2 * gl + 1] * inv_len - mu * mu, 0.f);
    float iv  = rsqrtf(var + 1e-5f);
    int cc = (int)((i0 / HW) % C);
    float ga = ldg_any(gamma, gb_off + cc, fw);
    float be = ldg_any(beta,  gb_off + cc, fw);
    float sc = iv * ga, sf = be - mu * iv * ga;
    uint4 u = *(const uint4*)(x + i0);
    float f[8];
    b2f2(u.x, f[0], f[1]); b2f2(u.y, f[2], f[3]);
    b2f2(u.z, f[4], f[5]); b2f2(u.w, f[6], f[7]);
#pragma unroll
    for (int j = 0; j < 8; ++j) f[j] = fmaxf(fmaf(f[j], sc, sf), 0.f);
    uint4 o;
    o.x = f2b(f[0]) | ((unsigned)f2b(f[1]) << 16);
    o.y = f2b(f[2]) | ((unsigned)f2b(f[3]) << 16);
    o.z = f2b(f[4]) | ((unsigned)f2b(f[5]) << 16);
    o.w = f2b(f[6]) | ((unsigned)f2b(f[7]) << 16);
    *(uint4*)(x + i0) = o;
}

// ---------------------------------------------------------------------------
__global__ void extract_params_k(const void* __restrict__ pred3, const int* __restrict__ flags,
                                 float* __restrict__ prm, int HW)
{
    const bool bf = flags[0] != 0;
    int tid = blockIdx.x * blockDim.x + threadIdx.x;
    if (tid >= 200 * 169) return;
    int p = tid / 169, c = tid - p * 169;
    int b = p / 100, i = p - b * 100;
    prm[tid] = ldg_any(pred3, ((size_t)b * 254 + 85 + c) * HW + i, bf);
}

__global__ void upsample_add_k(const bf16* __restrict__ src, bf16* __restrict__ dst,
                               int h, int w, int OH, int OW, long total)
{
    long i = (long)blockIdx.x * blockDim.x + threadIdx.x;
    if (i >= total) return;
    int ox = (int)(i % OW);
    long r = i / OW;
    int oy = (int)(r % OH);
    int nc = (int)(r / OH);
    float sy = oy * ((h - 1.f) / (OH - 1.f));
    float sx = ox * ((w - 1.f) / (OW - 1.f));
    int y0 = (int)sy; int y1 = min(y0 + 1, h - 1); float wy = sy - y0;
    int x0 = (int)sx; int x1 = min(x0 + 1, w - 1); float wx = sx - x0;
    const bf16* sp = src + (size_t)nc * h * w;
    float t0 = cvt(sp[y0 * w + x0]) * (1.f - wy) + cvt(sp[y1 * w + x0]) * wy;
    float t1 = cvt(sp[y0 * w + x1]) * (1.f - wy) + cvt(sp[y1 * w + x1]) * wy;
    float v = cvt(dst[i]) + t0 * (1.f - wx) + t1 * wx;
    dst[i] = __float2bfloat16(v);
}

__global__ void resize_out_k(const float* __restrict__ src, void* __restrict__ dst,
                             size_t dst_off, const int* __restrict__ flags,
                             int h, int w, int OH, int OW, long total)
{
    const bool bf = flags[0] != 0;
    long i = (long)blockIdx.x * blockDim.x + threadIdx.x;
    if (i >= total) return;
    int ox = (int)(i % OW);
    long r = i / OW;
    int oy = (int)(r % OH);
    int nc = (int)(r / OH);
    float sy = oy * ((h - 1.f) / (OH - 1.f));
    float sx = ox * ((w - 1.f) / (OW - 1.f));
    int y0 = (int)sy; int y1 = min(y0 + 1, h - 1); float wy = sy - y0;
    int x0 = (int)sx; int x1 = min(x0 + 1, w - 1); float wx = sx - x0;
    const float* sp = src + (size_t)nc * h * w;
    float t0 = sp[y0 * w + x0] * (1.f - wy) + sp[y1 * w + x0] * wy;
    float t1 = sp[y0 * w + x1] * (1.f - wy) + sp[y1 * w + x1] * wy;
    stg_any(dst, dst_off + (size_t)i, t0 * (1.f - wx) + t1 * wx, bf);
}

__global__ void cast_out_k(const bf16* __restrict__ src, void* __restrict__ dst,
                           size_t dst_off, const int* __restrict__ flags, long n)
{
    const bool bf = flags[0] != 0;
    long i = (long)blockIdx.x * blockDim.x + threadIdx.x;
    if (i < n) stg_any(dst, dst_off + (size_t)i, cvt(src[i]), bf);
}

__global__ void conv1x1_k(const bf16* __restrict__ in, const void* __restrict__ w,
                          const int* __restrict__ flags,
                          bf16* __restrict__ out, int N, int Cin, int Cout, int HW)
{
    const bool fw = flags[0] != 0;
    long total = (long)N * Cout * HW;
    long idx = (long)blockIdx.x * blockDim.x + threadIdx.x;
    if (idx >= total) return;
    int p  = (int)(idx % HW);
    int co = (int)((idx / HW) % Cout);
    int n  = (int)(idx / ((long)HW * Cout));
    float s = 0.f;
    const bf16* ip = in + (size_t)n * Cin * HW + p;
    for (int ci = 0; ci < Cin; ++ci)
        s = fmaf(ldg_any(w, (size_t)co * Cin + ci, fw), cvt(ip[(size_t)ci * HW]), s);
    out[idx] = __float2bfloat16(s);
}

__global__ __launch_bounds__(256) void dyn_conv_k(const bf16* __restrict__ mf,
                                                  const float* __restrict__ prm,
                                                  float* __restrict__ out, int H, int W)
{
    const int inst = blockIdx.y;
    __shared__ float p[169];
    if (threadIdx.x < 169) p[threadIdx.x] = prm[inst * 169 + threadIdx.x];
    __syncthreads();
    const int HW = H * W;
    const int pix = blockIdx.x * 256 + threadIdx.x;
    if (pix >= HW) return;
    const int b = inst / 100;
    float xin[10];
#pragma unroll
    for (int c = 0; c < 8; ++c) xin[c] = cvt(mf[((size_t)(b * 8 + c)) * HW + pix]);
    int yy = pix / W, xx = pix - yy * W;
    xin[8] = -1.f + 2.f * xx / (W - 1);
    xin[9] = -1.f + 2.f * yy / (H - 1);
    float h1[8];
#pragma unroll
    for (int o = 0; o < 8; ++o) {
        float s = p[152 + o];
#pragma unroll
        for (int c = 0; c < 10; ++c) s = fmaf(p[o * 10 + c], xin[c], s);
        h1[o] = fmaxf(s, 0.f);
    }
    float h2[8];
#pragma unroll
    for (int o = 0; o < 8; ++o) {
        float s = p[160 + o];
#pragma unroll
        for (int c = 0; c < 8; ++c) s = fmaf(p[80 + o * 8 + c], h1[c], s);
        h2[o] = fmaxf(s, 0.f);
    }
    float s = p[168];
#pragma unroll
    for (int c = 0; c < 8; ++c) s = fmaf(p[144 + c], h2[c], s);
    out[(size_t)inst * HW + pix] = s;
}

// ---------------------------------------------------------------------------
// host helpers
// ---------------------------------------------------------------------------
struct Norm { const float* st; const void* g; const void* b; size_t off; int cpg; int Gn; float inv; };

static inline void mconv(const void* in, int inm, const bf16* wrep, const Norm* nm,
                         const void* bias, const void* scale, int sidx,
                         void* out, int outm, size_t out_off, const int* flags,
                         int N, int Cin, int H, int W, int Cout, hipStream_t s)
{
    int cob = (Cout + 127) / 128, Cpad = cob * 128;
    dim3 g((W + 31) / 32, (H + 7) / 8, N * cob);
    conv3x3_mfma_k<<<g, 256, 0, s>>>(
        in, inm, wrep,
        nm ? nm->st : nullptr, nm ? nm->g : nullptr, nm ? nm->b : nullptr,
        nm ? nm->off : 0, nm ? nm->cpg : 1, nm ? nm->Gn : 1, nm ? nm->inv : 1.f,
        bias, scale, sidx, out, outm, out_off, flags, Cin, H, W, Cout, Cpad, cob);
}

static inline void run_stats(const bf16* x, float* st, int ngroups, int per_group, hipStream_t s)
{
    int chunks = per_group / 8192; if (chunks < 1) chunks = 1; if (chunks > 64) chunks = 64;
    gn_stats_v<<<dim3(ngroups, chunks), 256, 0, s>>>(x, st, per_group);
}

static inline void run_apply(bf16* x, const float* st, const void* g, const void* b,
                             size_t off, const int* flags, int N, int C, int Gn, int HW,
                             hipStream_t s)
{
    int per_group = (C / Gn) * HW;
    long nvec = ((long)N * C * HW) >> 3;
    gn_apply_v<<<(int)((nvec + 255) / 256), 256, 0, s>>>(
        x, st, g, b, off, flags, HW, C, per_group, 1.f / per_group, nvec);
}

static inline void repack(const void* w, const int* flags, bf16* dst,
                          int Cout, int Cin, hipStream_t s)
{
    int Cpad = ((Cout + 127) / 128) * 128;
    int total = 9 * Cpad * Cin;
    repack_k<<<(total + 255) / 256, 256, 0, s>>>(w, flags, dst, Cout, Cpad, Cin, total);
}

extern "C" void kernel_launch(void* const* d_in, const int* in_sizes, int n_in,
                              void* d_out, int out_size, void* d_ws, size_t ws_size,
                              hipStream_t stream)
{
    const void* f[5] = {d_in[0], d_in[1], d_in[2], d_in[3], d_in[4]};
    static const int Hs[5] = {96, 48, 24, 12, 6};
    static const int Wd[5] = {160, 80, 40, 20, 10};
    const void* head_w     = d_in[5];
    const void* head_gn_g  = d_in[6];
    const void* head_gn_b  = d_in[7];
    const void* head_out_w = d_in[8];
    const void* head_out_b = d_in[9];
    const void* scales     = d_in[10];
    const void* ref_w      = d_in[11];
    const void* ref_gn_g   = d_in[12];
    const void* ref_gn_b   = d_in[13];
    const void* tow_w      = d_in[14];
    const void* tow_gn_g   = d_in[15];
    const void* tow_gn_b   = d_in[16];
    const void* out_w      = d_in[17];
    const void* out_gn_g   = d_in[18];
    const void* out_gn_b   = d_in[19];

    size_t po[5]; size_t off = 0;
    for (int l = 0; l < 5; ++l) { po[l] = off; off += (size_t)2 * 254 * Hs[l] * Wd[l]; }
    size_t mf_off = off; off += 245760;
    size_t ml_off = off;

    // ---- workspace (~38 MB) ----
    bf16*  bufA  = (bf16*)d_ws;                 // 7,864,320 bf16
    bf16*  bufB  = bufA + 7864320;              // 7,864,320 bf16
    bf16*  mfeat = bufB + 7864320;              // 245,760 bf16
    float* prm   = (float*)(mfeat + 245760);    // 33,800 f32
    float* stats = prm + 33800;                 // 4,096 f32
    int*   flags = (int*)(stats + 4096);        // 16 int
    bf16*  wrep  = (bf16*)(flags + 16);         // 2,949,120 bf16
    float* dyn   = (float*)bufA;                // aliases bufA after last read

    bf16* wrepH  = wrep;                        // 4 x 589824 (head layers)
    bf16* wrepHO = wrep + 4 * 589824;           // 589824 (head_out, Cpad 256)
    bf16* wrepR  = wrep;                        // mask phase reuses region
    bf16* wrepT  = wrep + 3 * 294912;

    hipMemsetAsync(stats, 0, 4096 * sizeof(float), stream);
    detect_k<<<1, 64, 0, stream>>>((const unsigned int*)d_in[0], flags);

    float* sp = stats;

    // repack head weights once (reused across 5 levels)
    for (int l = 0; l < 4; ++l)
        repack((const char*)head_w, flags, wrepH + (size_t)l * 589824, 256, 256, stream),
        (void)0;
    // note: head_w layer offset is in *elements* of the runtime dtype -> must be
    // applied device-side; repack_k takes the base pointer + we bake the layer
    // offset into the src index via a per-layer base. Use a wrapper kernel call
    // with offset folded: easiest is pointer arithmetic only valid per-dtype, so
    // instead repack reads w with an element offset parameter baked into Cout*Cin*9
    // indexing. Here each head layer is a contiguous 589824-element slab, so we
    // re-launch repack_k with an offset pointer computed per dtype... not possible
    // host-side. Workaround: repack5_k below handles layered arrays.
    ;

    // The loop above repacked layer 0 four times (offset issue). Fix with explicit
    // layered repack: src element offset = l*589824 passed to kernel.
    // (repack_k cannot offset; use repack_off_k)
    // -- see repack_off_k definition note: we reuse repack_k by passing a
    //    pre-offset index base through Cpad trick is invalid; so do it properly:
    {
        // overwrite the bogus repacks with correct layered ones
        for (int l = 0; l < 4; ++l) {
            int total = 9 * 256 * 256;
            // repack with source element offset l*589824:
            // dst[i] = w[l*589824 + ((co*Cin+ci)*9+tap)]
            // implemented by repack_off_k
            extern __global__ void repack_off_k(const void*, size_t, const int*, bf16*, int, int, int, int);
            repack_off_k<<<(total + 255) / 256, 256, 0, stream>>>(
                head_w, (size_t)l * 589824, flags, wrepH + (size_t)l * 589824, 256, 256, 256, total);
        }
        {
            int total = 9 * 256 * 256;
            extern __global__ void repack_off_k(const void*, size_t, const int*, bf16*, int, int, int, int);
            repack_off_k<<<(total + 255) / 256, 256, 0, stream>>>(
                head_out_w, 0, flags, wrepHO, 254, 256, 256, total);
        }
    }

    // ---------------- head branches ----------------
    for (int lvl = 0; lvl < 5; ++lvl) {
        int H = Hs[lvl], W = Wd[lvl], HW = H * W;
        float inv_pg = 1.f / (8 * HW);
        mconv(f[lvl], 2, wrepH, nullptr, nullptr, nullptr, 0, bufA, 1, 0,
              flags, 2, 256, H, W, 256, stream);
        float* s_prev = sp; sp += 128;
        run_stats(bufA, s_prev, 64, 8 * HW, stream);
        bf16* a = bufA; bf16* bb = bufB;
        for (int l = 1; l < 4; ++l) {
            Norm nm{s_prev, head_gn_g, head_gn_b, (size_t)(l - 1) * 256, 8, 32, inv_pg};
            mconv(a, 1, wrepH + (size_t)l * 589824, &nm, nullptr, nullptr, 0,
                  bb, 1, 0, flags, 2, 256, H, W, 256, stream);
            s_prev = sp; sp += 128;
            run_stats(bb, s_prev, 64, 8 * HW, stream);
            bf16* tmp = a; a = bb; bb = tmp;
        }
        Norm nm{s_prev, head_gn_g, head_gn_b, (size_t)3 * 256, 8, 32, inv_pg};
        mconv(a, 1, wrepHO, &nm, head_out_b, scales, lvl, d_out, 2, po[lvl],
              flags, 2, 256, H, W, 254, stream);
        if (lvl == 0)
            extract_params_k<<<(200 * 169 + 255) / 256, 256, 0, stream>>>(d_out, flags, prm, HW);
    }

    // repack mask weights (head convs all enqueued; stream order protects region)
    {
        extern __global__ void repack_off_k(const void*, size_t, const int*, bf16*, int, int, int, int);
        for (int i = 0; i < 3; ++i) {
            int total = 9 * 128 * 256;
            repack_off_k<<<(total + 255) / 256, 256, 0, stream>>>(
                ref_w, (size_t)i * 294912, flags, wrepR + (size_t)i * 294912, 128, 128, 256, total);
        }
        for (int l = 0; l < 4; ++l) {
            int total = 9 * 128 * 128;
            repack_off_k<<<(total + 255) / 256, 256, 0, stream>>>(
                tow_w, (size_t)l * 147456, flags, wrepT + (size_t)l * 147456, 128, 128, 128, total);
        }
    }

    // ---------------- mask branch ----------------
    {
        int H = 96, W = 160, HW = H * W;
        // refine 0
        mconv(f[0], 2, wrepR, nullptr, nullptr, nullptr, 0, bufA, 1, 0,
              flags, 2, 256, H, W, 128, stream);
        float* s0 = sp; sp += 4;
        run_stats(bufA, s0, 2, 128 * HW, stream);
        run_apply(bufA, s0, ref_gn_g, ref_gn_b, 0, flags, 2, 128, 1, HW, stream);
        // refines 1,2 + upsample-add
        for (int i = 1; i < 3; ++i) {
            int h = Hs[i], w2 = Wd[i], hw = h * w2;
            mconv(f[i], 2, wrepR + (size_t)i * 294912, nullptr, nullptr, nullptr, 0,
                  bufB, 1, 0, flags, 2, 256, h, w2, 128, stream);
            float* si = sp; sp += 4;
            run_stats(bufB, si, 2, 128 * hw, stream);
            run_apply(bufB, si, ref_gn_g, ref_gn_b, (size_t)i * 128, flags, 2, 128, 1, hw, stream);
            long tot = (long)2 * 128 * HW;
            upsample_add_k<<<(int)((tot + 255) / 256), 256, 0, stream>>>(bufB, bufA, h, w2, H, W, tot);
        }
        // tower (normalized input in bufA)
        float inv_pg = 1.f / (128 * HW);
        mconv(bufA, 1, wrepT, nullptr, nullptr, nullptr, 0, bufB, 1, 0,
              flags, 2, 128, H, W, 128, stream);
        float* sT = sp; sp += 4;
        run_stats(bufB, sT, 2, 128 * HW, stream);
        bf16* a = bufB; bf16* bb = bufA;
        for (int l = 1; l < 4; ++l) {
            Norm nm{sT, tow_gn_g, tow_gn_b, (size_t)(l - 1) * 128, 128, 1, inv_pg};
            mconv(a, 1, wrepT + (size_t)l * 147456, &nm, nullptr, nullptr, 0,
                  bb, 1, 0, flags, 2, 128, H, W, 128, stream);
            sT = sp; sp += 4;
            run_stats(bb, sT, 2, 128 * HW, stream);
            bf16* tmp = a; a = bb; bb = tmp;
        }
        // tower output raw in a (= bufA after 3 swaps), stats sT for layer 3
        run_apply(a, sT, tow_gn_g, tow_gn_b, (size_t)3 * 128, flags, 2, 128, 1, HW, stream);
        conv1x1_k<<<(2 * 8 * HW + 255) / 256, 256, 0, stream>>>(a, out_w, flags, mfeat, 2, 128, 8, HW);
        float* sM = sp; sp += 4;
        run_stats(mfeat, sM, 2, 8 * HW, stream);
        run_apply(mfeat, sM, out_gn_g, out_gn_b, 0, flags, 2, 8, 1, HW, stream);
        cast_out_k<<<(2 * 8 * HW + 255) / 256, 256, 0, stream>>>(mfeat, d_out, mf_off, flags, (long)2 * 8 * HW);
        dyn_conv_k<<<dim3((HW + 255) / 256, 200), 256, 0, stream>>>(mfeat, prm, dyn, H, W);
        long nt = (long)200 * 192 * 320;
        resize_out_k<<<(int)((nt + 255) / 256), 256, 0, stream>>>(dyn, d_out, ml_off, flags, 96, 160, 192, 320, nt);
    }
}

// layered repack with source element offset (defined after use; HIP allows
// forward-declared __global__ via extern declarations above)
__global__ void repack_off_k(const void* __restrict__ w, size_t w_off,
                             const int* __restrict__ flags, bf16* __restrict__ dst,
                             int Cout, int Cpad, int Cin, int total)
{
    const bool fw = flags[0] != 0;
    int i = blockIdx.x * 256 + threadIdx.x;
    if (i >= total) return;
    int ci = i % Cin; int r = i / Cin; int co = r % Cpad; int tap = r / Cpad;
    float v = 0.f;
    if (co < Cout) v = ldg_any(w, w_off + ((size_t)co * Cin + ci) * 9 + tap, fw);
    dst[i] = __float2bfloat16(v);
}